// Round 14
// baseline (300.680 us; speedup 1.0000x reference)
//
#include <hip/hip_runtime.h>
#include <hip/hip_bf16.h>
#include <hip/hip_fp16.h>

#define SUP 2048
#define NB  256    // blocks in fused segacc: 1 per CU
#define LROWS 12   // packed conv rows kept in LDS (ch 0..23)

// Fixed-point scales
#define SC_CONV 1024.0f       // 2^10 (LDS 16-bit fields and global 32-bit fields)
#define SC_X0   512.0f
#define SC_XLO  256.0f
#define ISC_CONV (1.0f/1024.0f)

// 16-bit packed encode (LDS): sum of encodings == (sum a)*2^16 + (sum b).
__device__ __forceinline__ int enc2i(int qa, int qb) {
    return ((qa - (qb < 0 ? 1 : 0)) << 16) + (qb & 0xFFFF);
}
__device__ __forceinline__ int enc2f(float a, float b) {
    return enc2i(__float2int_rn(a), __float2int_rn(b));
}
// 32-bit packed encode (global u64): exact field sums, borrow-compensated.
__device__ __forceinline__ unsigned long long enc64(int qa, int qb) {
    unsigned int hi = (unsigned int)(qa - (qb < 0 ? 1 : 0));
    return ((unsigned long long)hi << 32) | (unsigned int)qb;
}
__device__ __forceinline__ int qrn(float v) { return __float2int_rn(v); }

// ---------------------------------------------------------------------------
// K2 (fused): single pass over conv. DS/L2 atomic-pipe SPLIT:
//  - ch 0..23 -> 12 packed int32 LDS atomics/px (96 KiB LDS, 1 block/CU)
//  - ch 24..31 (4 u64) + (x0,x1) (1 u64) + (count,x2) (1 u64) -> 6
//    global_atomic_add_u64/px into gacc[6][SUP] (96 KB, L2-resident, exact).
// The DS pipe (measured ~115 cyc per atomic wave-instruction, unpipelined)
// carries 2/3 of the old load; the L2 atomic pipe absorbs the rest in
// parallel. Flush: LDS rows decode -> fp16 pbuf[NB][24][SUP].
// ---------------------------------------------------------------------------
__global__ __launch_bounds__(1024) void k_segfused(const float* __restrict__ conv,
                                                   const float* __restrict__ x,
                                                   const int* __restrict__ ids,
                                                   float* __restrict__ accum,
                                                   unsigned long long* __restrict__ gacc,
                                                   __half* __restrict__ pbuf,
                                                   int npix) {
    __shared__ int sacc[LROWS * SUP];  // 96 KiB
    for (int i = threadIdx.x; i < LROWS * SUP; i += blockDim.x) sacc[i] = 0;
    __syncthreads();

    int per = ((npix + (int)gridDim.x - 1) / (int)gridDim.x + 1) & ~1;  // even
    int start = blockIdx.x * per;
    int end = min(start + per, npix);
    int stride2 = (int)blockDim.x * 2;

    int p = start + (int)threadIdx.x * 2;
    for (; p + 1 < end; p += stride2) {
        int2 id2 = *(const int2*)(ids + p);
        float2 cv[32];
        float s0 = 0.f, s1 = 0.f;
#pragma unroll
        for (int c = 0; c < 32; ++c) {
            cv[c] = *(const float2*)(conv + (size_t)c * npix + p);
            s0 += cv[c].x * cv[c].x;
            s1 += cv[c].y * cv[c].y;
        }
        float w0 = SC_CONV / fmaxf(sqrtf(s0), 1e-12f);
        float w1 = SC_CONV / fmaxf(sqrtf(s1), 1e-12f);
        // LDS part: ch 0..23
#pragma unroll
        for (int r = 0; r < LROWS; ++r) {
            float2 a = cv[2 * r], b = cv[2 * r + 1];
            atomicAdd(&sacc[r * SUP + id2.x], enc2f(a.x * w0, b.x * w0));
            atomicAdd(&sacc[r * SUP + id2.y], enc2f(a.y * w1, b.y * w1));
        }
        // Global part: ch 24..31
#pragma unroll
        for (int k = 0; k < 4; ++k) {
            float2 a = cv[24 + 2 * k], b = cv[25 + 2 * k];
            atomicAdd(&gacc[k * SUP + id2.x], enc64(qrn(a.x * w0), qrn(b.x * w0)));
            atomicAdd(&gacc[k * SUP + id2.y], enc64(qrn(a.y * w1), qrn(b.y * w1)));
        }
        float2 x0 = *(const float2*)(x + p);
        float2 x1 = *(const float2*)(x + (size_t)npix + p);
        float2 x2 = *(const float2*)(x + (size_t)2 * npix + p);
        atomicAdd(&gacc[4 * SUP + id2.x],
                  enc64(qrn(x0.x * SC_CONV), qrn(x1.x * SC_CONV)));
        atomicAdd(&gacc[4 * SUP + id2.y],
                  enc64(qrn(x0.y * SC_CONV), qrn(x1.y * SC_CONV)));
        atomicAdd(&gacc[5 * SUP + id2.x], enc64(1, qrn(x2.x * SC_CONV)));
        atomicAdd(&gacc[5 * SUP + id2.y], enc64(1, qrn(x2.y * SC_CONV)));
    }
    // odd-pixel tail
    if (p == end - 1) {
        int s = ids[p];
        float cvv[32];
        float ss = 0.f;
#pragma unroll
        for (int c = 0; c < 32; ++c) {
            cvv[c] = conv[(size_t)c * npix + p];
            ss += cvv[c] * cvv[c];
        }
        float w = SC_CONV / fmaxf(sqrtf(ss), 1e-12f);
#pragma unroll
        for (int r = 0; r < LROWS; ++r)
            atomicAdd(&sacc[r * SUP + s], enc2f(cvv[2 * r] * w, cvv[2 * r + 1] * w));
#pragma unroll
        for (int k = 0; k < 4; ++k)
            atomicAdd(&gacc[k * SUP + s],
                      enc64(qrn(cvv[24 + 2 * k] * w), qrn(cvv[25 + 2 * k] * w)));
        atomicAdd(&gacc[4 * SUP + s],
                  enc64(qrn(x[p] * SC_CONV), qrn(x[(size_t)npix + p] * SC_CONV)));
        atomicAdd(&gacc[5 * SUP + s],
                  enc64(1, qrn(x[(size_t)2 * npix + p] * SC_CONV)));
    }
    __syncthreads();

    // decode LDS rows + flush (coalesced: i = row*SUP + s)
    for (int i = threadIdx.x; i < LROWS * SUP; i += blockDim.x) {
        int S = sacc[i];
        int qb = (int)(short)(S & 0xFFFF);
        int qa = (S - qb) >> 16;
        int row = i >> 11;
        int s = i & (SUP - 1);
        float fhi = (float)qa * ISC_CONV;
        float flo = (float)qb * ISC_CONV;
        if (pbuf) {
            __half* dst = pbuf + (size_t)blockIdx.x * 24 * SUP;
            dst[(2 * row) * SUP + s] = __float2half(fhi);
            dst[(2 * row + 1) * SUP + s] = __float2half(flo);
        } else {
            unsafeAtomicAdd(&accum[(2 * row) * SUP + s], fhi);
            unsafeAtomicAdd(&accum[(2 * row + 1) * SUP + s], flo);
        }
    }
}

// ---------------------------------------------------------------------------
// K2b: build accum[36][SUP]: rows 0..23 from fp16 pbuf partial sums,
// rows 24..35 decoded from the exact u64 global accumulator.
// 144 blocks x 64 threads, 8 elements/thread.
// ---------------------------------------------------------------------------
__global__ __launch_bounds__(64) void k_reduce(const __half* __restrict__ pbuf,
                                               const unsigned long long* __restrict__ gacc,
                                               float* __restrict__ accum) {
    int j8 = (blockIdx.x * 64 + threadIdx.x) * 8;
    if (j8 >= 36 * SUP) return;
    int row = j8 >> 11;          // all 8 elements share one row (2048 % 8 == 0)
    if (row < 24) {
        float s[8];
#pragma unroll
        for (int k = 0; k < 8; ++k) s[k] = 0.f;
        for (int b = 0; b < NB; ++b) {
            uint4 u = *(const uint4*)(pbuf + (size_t)b * 24 * SUP + j8);
            __half2 h0 = *reinterpret_cast<__half2*>(&u.x);
            __half2 h1 = *reinterpret_cast<__half2*>(&u.y);
            __half2 h2 = *reinterpret_cast<__half2*>(&u.z);
            __half2 h3 = *reinterpret_cast<__half2*>(&u.w);
            float2 f0 = __half22float2(h0), f1 = __half22float2(h1);
            float2 f2 = __half22float2(h2), f3 = __half22float2(h3);
            s[0] += f0.x; s[1] += f0.y; s[2] += f1.x; s[3] += f1.y;
            s[4] += f2.x; s[5] += f2.y; s[6] += f3.x; s[7] += f3.y;
        }
        float4 o0 = {s[0], s[1], s[2], s[3]};
        float4 o1 = {s[4], s[5], s[6], s[7]};
        *(float4*)(accum + j8) = o0;
        *(float4*)(accum + j8 + 4) = o1;
    } else {
        int sbase = j8 & (SUP - 1);
#pragma unroll
        for (int k = 0; k < 8; ++k) {
            int s = sbase + k;
            unsigned long long S;
            bool useHi;
            float scale = ISC_CONV;
            if (row < 32) {
                int slot = (row - 24) >> 1;
                S = gacc[slot * SUP + s];
                useHi = (((row - 24) & 1) == 0);
            } else if (row == 32) { S = gacc[4 * SUP + s]; useHi = true; }
            else if (row == 33)   { S = gacc[4 * SUP + s]; useHi = false; }
            else if (row == 34)   { S = gacc[5 * SUP + s]; useHi = false; }
            else                  { S = gacc[5 * SUP + s]; useHi = true; scale = 1.0f; }
            int lo = (int)(unsigned int)(S & 0xFFFFFFFFull);
            long long hi = ((long long)S - (long long)lo) >> 32;
            float val = (useHi ? (float)hi : (float)lo) * scale;
            accum[j8 + k] = val;
        }
    }
}

// ---------------------------------------------------------------------------
// K3: per-segment finalize + conv1d. 8 blocks x 256 segments, halo'd LDS tile.
// ---------------------------------------------------------------------------
__device__ __forceinline__ void compute_col(const float* __restrict__ accum,
                                            const float* __restrict__ vit,
                                            int g, float* __restrict__ col) {
    if (g < 0 || g >= SUP) {
#pragma unroll
        for (int c = 0; c < 64; ++c) col[c] = 0.f;
        return;
    }
    float cnt = fmaxf(accum[35 * SUP + g], 1.0f);
    float rc = 1.0f / cnt;
#pragma unroll
    for (int c = 0; c < 32; ++c) col[c] = accum[c * SUP + g] * rc;
    float vs = 0.f;
#pragma unroll
    for (int c = 0; c < 32; ++c) {
        float v = vit[g * 32 + c];
        col[32 + c] = v;
        vs += v * v;
    }
    float vinv = 1.0f / fmaxf(sqrtf(vs), 1e-12f);
#pragma unroll
    for (int c = 0; c < 32; ++c) col[32 + c] *= vinv;
    float ssq = 0.f;
#pragma unroll
    for (int c = 0; c < 64; ++c) ssq += col[c] * col[c];
    float ainv = 1.0f / fmaxf(sqrtf(ssq), 1e-12f);
#pragma unroll
    for (int c = 0; c < 64; ++c) col[c] *= ainv;
}

__global__ __launch_bounds__(256) void k_finalconv(const float* __restrict__ accum,
                                                   const float* __restrict__ vit,
                                                   const float* __restrict__ w,
                                                   const float* __restrict__ bias,
                                                   float* __restrict__ allF_out,
                                                   float* __restrict__ xf_out,
                                                   float* __restrict__ z_out) {
    __shared__ float L[258][65];
    __shared__ float sw[192];
    int t = threadIdx.x;
    int b0 = blockIdx.x * 256;
    if (t < 192) sw[t] = w[t];

    float col[64];
    int g = b0 + t;
    compute_col(accum, vit, g, col);
#pragma unroll
    for (int c = 0; c < 64; ++c) L[t + 1][c] = col[c];
#pragma unroll
    for (int c = 0; c < 64; ++c) allF_out[c * SUP + g] = col[c];
    {
        float cnt = fmaxf(accum[35 * SUP + g], 1.0f);
        float rc = 1.0f / cnt;
#pragma unroll
        for (int c = 0; c < 3; ++c)
            xf_out[c * SUP + g] = accum[(32 + c) * SUP + g] * rc;
    }
    if (t == 0) {
        compute_col(accum, vit, b0 - 1, col);
#pragma unroll
        for (int c = 0; c < 64; ++c) L[0][c] = col[c];
    }
    if (t == 255) {
        compute_col(accum, vit, b0 + 256, col);
#pragma unroll
        for (int c = 0; c < 64; ++c) L[257][c] = col[c];
    }
    __syncthreads();

    float acc = bias[0];
#pragma unroll
    for (int c = 0; c < 64; ++c) {
        acc += sw[c * 3] * L[t][c] + sw[c * 3 + 1] * L[t + 1][c]
             + sw[c * 3 + 2] * L[t + 2][c];
    }
    z_out[b0 + t] = acc;
}

// ---------------------------------------------------------------------------
// K4: BN (batch stats over 2048) + sigmoid + gap.
// ---------------------------------------------------------------------------
__global__ __launch_bounds__(512) void k_head2(const float* __restrict__ z,
                                               const float* __restrict__ gamma,
                                               const float* __restrict__ beta,
                                               float* __restrict__ out) {
    __shared__ float red[8];
    __shared__ float bc[2];
    int tid = threadIdx.x;
    int lane = tid & 63, wid = tid >> 6;

    float zs[4];
#pragma unroll
    for (int j = 0; j < 4; ++j) zs[j] = z[j * 512 + tid];

    float s1 = zs[0] + zs[1] + zs[2] + zs[3];
#pragma unroll
    for (int o = 32; o > 0; o >>= 1) s1 += __shfl_down(s1, o);
    if (lane == 0) red[wid] = s1;
    __syncthreads();
    if (tid == 0) {
        float t = 0.f;
        for (int i = 0; i < 8; ++i) t += red[i];
        bc[0] = t / (float)SUP;
    }
    __syncthreads();
    float mu = bc[0];

    float s2 = 0.f;
#pragma unroll
    for (int j = 0; j < 4; ++j) { float d = zs[j] - mu; s2 += d * d; }
#pragma unroll
    for (int o = 32; o > 0; o >>= 1) s2 += __shfl_down(s2, o);
    __syncthreads();
    if (lane == 0) red[wid] = s2;
    __syncthreads();
    if (tid == 0) {
        float t = 0.f;
        for (int i = 0; i < 8; ++i) t += red[i];
        bc[1] = t / (float)SUP;
    }
    __syncthreads();
    float var = bc[1];

    float invstd = rsqrtf(var + 1e-5f);
    float gm = gamma[0], bt = beta[0];
    float gsum = 0.f;
#pragma unroll
    for (int j = 0; j < 4; ++j) {
        int p = j * 512 + tid;
        float zn = gm * (zs[j] - mu) * invstd + bt;
        float r = 1.0f / (1.0f + expf(-zn));
        out[p] = r;
        gsum += r;
    }
#pragma unroll
    for (int o = 32; o > 0; o >>= 1) gsum += __shfl_down(gsum, o);
    __syncthreads();
    if (lane == 0) red[wid] = gsum;
    __syncthreads();
    if (tid == 0) {
        float t = 0.f;
        for (int i = 0; i < 8; ++i) t += red[i];
        out[SUP] = t / (float)SUP;
    }
}

extern "C" void kernel_launch(void* const* d_in, const int* in_sizes, int n_in,
                              void* d_out, int out_size, void* d_ws, size_t ws_size,
                              hipStream_t stream) {
    const float* x     = (const float*)d_in[0];
    const float* conv  = (const float*)d_in[1];
    const float* vit   = (const float*)d_in[2];
    const int*   ids   = (const int*)d_in[3];
    const float* w     = (const float*)d_in[4];
    const float* b     = (const float*)d_in[5];
    const float* gamma = (const float*)d_in[6];
    const float* beta  = (const float*)d_in[7];
    float* out = (float*)d_out;

    int npix = in_sizes[3];  // B*H*W = 1048576

    // ws: accum(36*SUP f32) | zbuf(SUP f32) | gacc(6*SUP u64) | pbuf(NB*24*SUP half)
    float* accum = (float*)d_ws;
    float* zbuf = accum + 36 * SUP;
    unsigned long long* gacc = (unsigned long long*)(zbuf + SUP);
    __half* pbuf = (__half*)(gacc + 6 * SUP);

    size_t need = (36 * SUP + SUP) * sizeof(float) + 6 * SUP * 8
                + (size_t)NB * 24 * SUP * sizeof(__half);
    bool useP = ws_size >= need;

    hipMemsetAsync(gacc, 0, 6 * SUP * sizeof(unsigned long long), stream);
    if (!useP) hipMemsetAsync(accum, 0, 36 * SUP * sizeof(float), stream);

    k_segfused<<<NB, 1024, 0, stream>>>(conv, x, ids, accum, gacc,
                                        useP ? pbuf : (__half*)nullptr, npix);
    if (useP) {
        k_reduce<<<(36 * SUP / 8 + 63) / 64, 64, 0, stream>>>(pbuf, gacc, accum);
    } else {
        // fallback: rows 24..35 still need decode into accum
        k_reduce<<<(36 * SUP / 8 + 63) / 64, 64, 0, stream>>>((const __half*)nullptr, gacc, accum);
    }

    float* allF = out + SUP + 1;                // out offset 2049
    float* xf = allF + 64 * SUP;                // out offset 133121
    k_finalconv<<<SUP / 256, 256, 0, stream>>>(accum, vit, w, b, allF, xf, zbuf);

    k_head2<<<1, 512, 0, stream>>>(zbuf, gamma, beta, out);
}

// Round 15
// 75.817 us; speedup vs baseline: 3.9658x; 3.9658x over previous
//
#include <hip/hip_runtime.h>
#include <hip/hip_bf16.h>
#include <hip/hip_fp16.h>

#define SUP 2048
#define NB  256    // blocks in fused segacc: 1 per CU

// Fixed-point scales
#define SC_CONV 1024.0f       // 2^10, |normalized conv| <= 1
#define SC_X0   512.0f        // 2^9  (high field)
#define SC_XLO  256.0f        // 2^8  (low field: |block-bin sum| < 2^15)
#define ISC_CONV (1.0f/1024.0f)
#define ISC_X0   (1.0f/512.0f)
#define ISC_XLO  (1.0f/256.0f)

// Exact packed encode: sum of encodings == (sum a)*2^16 + (sum b) in int32
// (borrow from negative low fields pre-compensated).
__device__ __forceinline__ int enc2i(int qa, int qb) {
    return ((qa - (qb < 0 ? 1 : 0)) << 16) + (qb & 0xFFFF);
}
__device__ __forceinline__ int enc2f(float a, float b) {
    return enc2i(__float2int_rn(a), __float2int_rn(b));
}

// ---------------------------------------------------------------------------
// K2 (fused): single pass over conv (best measured config: 75.5 us total).
// Per 2 pixels: load all 32 channels (float2/lane), inv L2 norm inline,
// 18 packed int32 LDS atomics per pixel. LDS 18 x 2048 x int = 144 KiB
// -> 1 block/CU.
//   rows 0..15: conv channel pairs (2r, 2r+1) @2^10
//   row 16: (x0 @2^9 hi, x1 @2^8 lo)     row 17: (count hi, x2 @2^8 lo)
// Flush decodes -> fp16 pbuf[NB][36][SUP] (or f32 global atomics fallback).
// DS-atomic wall: ~1152 atomic wave-instr/CU x ~115-160 cyc = the kernel's
// floor; conv read (~21 us) hides under it. Exhaustively probed R6-R14.
// ---------------------------------------------------------------------------
__global__ __launch_bounds__(1024) void k_segfused(const float* __restrict__ conv,
                                                   const float* __restrict__ x,
                                                   const int* __restrict__ ids,
                                                   float* __restrict__ accum,
                                                   __half* __restrict__ pbuf,
                                                   int npix) {
    __shared__ int sacc[18 * SUP];  // 144 KiB
    for (int i = threadIdx.x; i < 18 * SUP; i += blockDim.x) sacc[i] = 0;
    __syncthreads();

    int per = ((npix + (int)gridDim.x - 1) / (int)gridDim.x + 1) & ~1;  // even
    int start = blockIdx.x * per;
    int end = min(start + per, npix);
    int stride2 = (int)blockDim.x * 2;

    int p = start + (int)threadIdx.x * 2;
    for (; p + 1 < end; p += stride2) {
        int2 id2 = *(const int2*)(ids + p);
        float2 cv[32];
        float s0 = 0.f, s1 = 0.f;
#pragma unroll
        for (int c = 0; c < 32; ++c) {
            cv[c] = *(const float2*)(conv + (size_t)c * npix + p);
            s0 += cv[c].x * cv[c].x;
            s1 += cv[c].y * cv[c].y;
        }
        float i0 = 1.0f / fmaxf(sqrtf(s0), 1e-12f);
        float i1 = 1.0f / fmaxf(sqrtf(s1), 1e-12f);
#pragma unroll
        for (int r = 0; r < 16; ++r) {
            float2 a = cv[2 * r], b = cv[2 * r + 1];
            atomicAdd(&sacc[r * SUP + id2.x],
                      enc2f(a.x * i0 * SC_CONV, b.x * i0 * SC_CONV));
            atomicAdd(&sacc[r * SUP + id2.y],
                      enc2f(a.y * i1 * SC_CONV, b.y * i1 * SC_CONV));
        }
        float2 x0 = *(const float2*)(x + p);
        float2 x1 = *(const float2*)(x + (size_t)npix + p);
        float2 x2 = *(const float2*)(x + (size_t)2 * npix + p);
        atomicAdd(&sacc[16 * SUP + id2.x], enc2f(x0.x * SC_X0, x1.x * SC_XLO));
        atomicAdd(&sacc[16 * SUP + id2.y], enc2f(x0.y * SC_X0, x1.y * SC_XLO));
        atomicAdd(&sacc[17 * SUP + id2.x], enc2i(1, __float2int_rn(x2.x * SC_XLO)));
        atomicAdd(&sacc[17 * SUP + id2.y], enc2i(1, __float2int_rn(x2.y * SC_XLO)));
    }
    // odd-pixel tail (at most one pixel; exactly one thread matches)
    if (p == end - 1) {
        int s = ids[p];
        float cvv[32];
        float ss = 0.f;
#pragma unroll
        for (int c = 0; c < 32; ++c) {
            cvv[c] = conv[(size_t)c * npix + p];
            ss += cvv[c] * cvv[c];
        }
        float iv = 1.0f / fmaxf(sqrtf(ss), 1e-12f);
#pragma unroll
        for (int r = 0; r < 16; ++r)
            atomicAdd(&sacc[r * SUP + s],
                      enc2f(cvv[2 * r] * iv * SC_CONV, cvv[2 * r + 1] * iv * SC_CONV));
        atomicAdd(&sacc[16 * SUP + s],
                  enc2f(x[p] * SC_X0, x[(size_t)npix + p] * SC_XLO));
        atomicAdd(&sacc[17 * SUP + s],
                  enc2i(1, __float2int_rn(x[(size_t)2 * npix + p] * SC_XLO)));
    }
    __syncthreads();

    // decode + flush
    for (int i = threadIdx.x; i < 18 * SUP; i += blockDim.x) {
        int S = sacc[i];
        int qb = (int)(short)(S & 0xFFFF);
        int qa = (S - qb) >> 16;
        int row = i >> 11;
        int s = i & (SUP - 1);
        int hi_row, lo_row;
        float fhi, flo;
        if (row < 16) {
            hi_row = 2 * row; lo_row = 2 * row + 1;
            fhi = (float)qa * ISC_CONV;
            flo = (float)qb * ISC_CONV;
        } else if (row == 16) {
            hi_row = 32; lo_row = 33;
            fhi = (float)qa * ISC_X0;
            flo = (float)qb * ISC_XLO;
        } else {
            hi_row = 35; lo_row = 34;
            fhi = (float)qa;              // count
            flo = (float)qb * ISC_XLO;    // x2
        }
        if (pbuf) {
            __half* dst = pbuf + (size_t)blockIdx.x * 36 * SUP;
            dst[hi_row * SUP + s] = __float2half(fhi);
            dst[lo_row * SUP + s] = __float2half(flo);
        } else {
            unsafeAtomicAdd(&accum[hi_row * SUP + s], fhi);
            unsafeAtomicAdd(&accum[lo_row * SUP + s], flo);
        }
    }
}

// ---------------------------------------------------------------------------
// K2b: reduce fp16 per-block partials -> accum[36][SUP]. 8 elements/thread.
// 144 blocks x 64 threads: spreads the 37.7 MB stream over many CUs.
// ---------------------------------------------------------------------------
__global__ __launch_bounds__(64) void k_reduce(const __half* __restrict__ pbuf,
                                               float* __restrict__ accum) {
    int j8 = (blockIdx.x * 64 + threadIdx.x) * 8;
    if (j8 >= 36 * SUP) return;
    float s[8];
#pragma unroll
    for (int k = 0; k < 8; ++k) s[k] = 0.f;
    for (int b = 0; b < NB; ++b) {
        uint4 u = *(const uint4*)(pbuf + (size_t)b * 36 * SUP + j8);
        __half2 h0 = *reinterpret_cast<__half2*>(&u.x);
        __half2 h1 = *reinterpret_cast<__half2*>(&u.y);
        __half2 h2 = *reinterpret_cast<__half2*>(&u.z);
        __half2 h3 = *reinterpret_cast<__half2*>(&u.w);
        float2 f0 = __half22float2(h0), f1 = __half22float2(h1);
        float2 f2 = __half22float2(h2), f3 = __half22float2(h3);
        s[0] += f0.x; s[1] += f0.y; s[2] += f1.x; s[3] += f1.y;
        s[4] += f2.x; s[5] += f2.y; s[6] += f3.x; s[7] += f3.y;
    }
    float4 o0 = {s[0], s[1], s[2], s[3]};
    float4 o1 = {s[4], s[5], s[6], s[7]};
    *(float4*)(accum + j8) = o0;
    *(float4*)(accum + j8 + 4) = o1;
}

// ---------------------------------------------------------------------------
// K3: per-segment finalize + conv1d. 8 blocks x 256 segments, halo'd LDS tile.
// ---------------------------------------------------------------------------
__device__ __forceinline__ void compute_col(const float* __restrict__ accum,
                                            const float* __restrict__ vit,
                                            int g, float* __restrict__ col) {
    if (g < 0 || g >= SUP) {
#pragma unroll
        for (int c = 0; c < 64; ++c) col[c] = 0.f;
        return;
    }
    float cnt = fmaxf(accum[35 * SUP + g], 1.0f);
    float rc = 1.0f / cnt;
#pragma unroll
    for (int c = 0; c < 32; ++c) col[c] = accum[c * SUP + g] * rc;
    float vs = 0.f;
#pragma unroll
    for (int c = 0; c < 32; ++c) {
        float v = vit[g * 32 + c];
        col[32 + c] = v;
        vs += v * v;
    }
    float vinv = 1.0f / fmaxf(sqrtf(vs), 1e-12f);
#pragma unroll
    for (int c = 0; c < 32; ++c) col[32 + c] *= vinv;
    float ssq = 0.f;
#pragma unroll
    for (int c = 0; c < 64; ++c) ssq += col[c] * col[c];
    float ainv = 1.0f / fmaxf(sqrtf(ssq), 1e-12f);
#pragma unroll
    for (int c = 0; c < 64; ++c) col[c] *= ainv;
}

__global__ __launch_bounds__(256) void k_finalconv(const float* __restrict__ accum,
                                                   const float* __restrict__ vit,
                                                   const float* __restrict__ w,
                                                   const float* __restrict__ bias,
                                                   float* __restrict__ allF_out,
                                                   float* __restrict__ xf_out,
                                                   float* __restrict__ z_out) {
    __shared__ float L[258][65];
    __shared__ float sw[192];
    int t = threadIdx.x;
    int b0 = blockIdx.x * 256;
    if (t < 192) sw[t] = w[t];

    float col[64];
    int g = b0 + t;
    compute_col(accum, vit, g, col);
#pragma unroll
    for (int c = 0; c < 64; ++c) L[t + 1][c] = col[c];
#pragma unroll
    for (int c = 0; c < 64; ++c) allF_out[c * SUP + g] = col[c];
    {
        float cnt = fmaxf(accum[35 * SUP + g], 1.0f);
        float rc = 1.0f / cnt;
#pragma unroll
        for (int c = 0; c < 3; ++c)
            xf_out[c * SUP + g] = accum[(32 + c) * SUP + g] * rc;
    }
    if (t == 0) {
        compute_col(accum, vit, b0 - 1, col);
#pragma unroll
        for (int c = 0; c < 64; ++c) L[0][c] = col[c];
    }
    if (t == 255) {
        compute_col(accum, vit, b0 + 256, col);
#pragma unroll
        for (int c = 0; c < 64; ++c) L[257][c] = col[c];
    }
    __syncthreads();

    float acc = bias[0];
#pragma unroll
    for (int c = 0; c < 64; ++c) {
        acc += sw[c * 3] * L[t][c] + sw[c * 3 + 1] * L[t + 1][c]
             + sw[c * 3 + 2] * L[t + 2][c];
    }
    z_out[b0 + t] = acc;
}

// ---------------------------------------------------------------------------
// K4: BN (batch stats over 2048) + sigmoid + gap.
// ---------------------------------------------------------------------------
__global__ __launch_bounds__(512) void k_head2(const float* __restrict__ z,
                                               const float* __restrict__ gamma,
                                               const float* __restrict__ beta,
                                               float* __restrict__ out) {
    __shared__ float red[8];
    __shared__ float bc[2];
    int tid = threadIdx.x;
    int lane = tid & 63, wid = tid >> 6;

    float zs[4];
#pragma unroll
    for (int j = 0; j < 4; ++j) zs[j] = z[j * 512 + tid];

    float s1 = zs[0] + zs[1] + zs[2] + zs[3];
#pragma unroll
    for (int o = 32; o > 0; o >>= 1) s1 += __shfl_down(s1, o);
    if (lane == 0) red[wid] = s1;
    __syncthreads();
    if (tid == 0) {
        float t = 0.f;
        for (int i = 0; i < 8; ++i) t += red[i];
        bc[0] = t / (float)SUP;
    }
    __syncthreads();
    float mu = bc[0];

    float s2 = 0.f;
#pragma unroll
    for (int j = 0; j < 4; ++j) { float d = zs[j] - mu; s2 += d * d; }
#pragma unroll
    for (int o = 32; o > 0; o >>= 1) s2 += __shfl_down(s2, o);
    __syncthreads();
    if (lane == 0) red[wid] = s2;
    __syncthreads();
    if (tid == 0) {
        float t = 0.f;
        for (int i = 0; i < 8; ++i) t += red[i];
        bc[1] = t / (float)SUP;
    }
    __syncthreads();
    float var = bc[1];

    float invstd = rsqrtf(var + 1e-5f);
    float gm = gamma[0], bt = beta[0];
    float gsum = 0.f;
#pragma unroll
    for (int j = 0; j < 4; ++j) {
        int p = j * 512 + tid;
        float zn = gm * (zs[j] - mu) * invstd + bt;
        float r = 1.0f / (1.0f + expf(-zn));
        out[p] = r;
        gsum += r;
    }
#pragma unroll
    for (int o = 32; o > 0; o >>= 1) gsum += __shfl_down(gsum, o);
    __syncthreads();
    if (lane == 0) red[wid] = gsum;
    __syncthreads();
    if (tid == 0) {
        float t = 0.f;
        for (int i = 0; i < 8; ++i) t += red[i];
        out[SUP] = t / (float)SUP;
    }
}

extern "C" void kernel_launch(void* const* d_in, const int* in_sizes, int n_in,
                              void* d_out, int out_size, void* d_ws, size_t ws_size,
                              hipStream_t stream) {
    const float* x     = (const float*)d_in[0];
    const float* conv  = (const float*)d_in[1];
    const float* vit   = (const float*)d_in[2];
    const int*   ids   = (const int*)d_in[3];
    const float* w     = (const float*)d_in[4];
    const float* b     = (const float*)d_in[5];
    const float* gamma = (const float*)d_in[6];
    const float* beta  = (const float*)d_in[7];
    float* out = (float*)d_out;

    int npix = in_sizes[3];  // B*H*W = 1048576

    // ws layout: accum (36*SUP f32) | zbuf (SUP f32) | pbuf (NB*36*SUP halves)
    float* accum = (float*)d_ws;
    float* zbuf = accum + 36 * SUP;
    __half* pbuf = (__half*)(zbuf + SUP);

    size_t need = (36 * SUP + SUP) * sizeof(float)
                + (size_t)NB * 36 * SUP * sizeof(__half);
    bool useP = ws_size >= need;

    if (!useP) hipMemsetAsync(accum, 0, 36 * SUP * sizeof(float), stream);

    k_segfused<<<NB, 1024, 0, stream>>>(conv, x, ids, accum,
                                        useP ? pbuf : (__half*)nullptr, npix);
    if (useP) {
        k_reduce<<<(36 * SUP / 8 + 63) / 64, 64, 0, stream>>>(pbuf, accum);
    }

    float* allF = out + SUP + 1;                // out offset 2049
    float* xf = allF + 64 * SUP;                // out offset 133121
    k_finalconv<<<SUP / 256, 256, 0, stream>>>(accum, vit, w, b, allF, xf, zbuf);

    k_head2<<<1, 512, 0, stream>>>(zbuf, gamma, beta, out);
}